// Round 2
// baseline (26134.225 us; speedup 1.0000x reference)
//
#include <hip/hip_runtime.h>

// Average-trace constant from the Python module (length 120).
__device__ __constant__ float AVG_D[120] = {
    0.0256f,0.0823f,0.1157f,0.1315f,0.1366f,0.1369f,0.1347f,0.1308f,0.1259f,0.1205f,
    0.1146f,0.1086f,0.1028f,0.0970f,0.0913f,0.0858f,0.0805f,0.0756f,0.0708f,0.0664f,
    0.0623f,0.0584f,0.0549f,0.0515f,0.0485f,0.0456f,0.0429f,0.0404f,0.0381f,0.0360f,
    0.0340f,0.0321f,0.0304f,0.0287f,0.0272f,0.0258f,0.0245f,0.0233f,0.0222f,0.0211f,
    0.0201f,0.0191f,0.0182f,0.0173f,0.0165f,0.0158f,0.0150f,0.0143f,0.0137f,0.0130f,
    0.0125f,0.0119f,0.0114f,0.0108f,0.0104f,0.0099f,0.0095f,0.0091f,0.0087f,0.0083f,
    0.0080f,0.0077f,0.0074f,0.0071f,0.0068f,0.0065f,0.0062f,0.0060f,0.0058f,0.0055f,
    0.0053f,0.0050f,0.0049f,0.0047f,0.0045f,0.0044f,0.0042f,0.0040f,0.0039f,0.0038f,
    0.0036f,0.0034f,0.0033f,0.0032f,0.0031f,0.0030f,0.0029f,0.0028f,0.0027f,0.0026f,
    0.0025f,0.0024f,0.0023f,0.0022f,0.0021f,0.0021f,0.0020f,0.0019f,0.0018f,0.0018f,
    0.0017f,0.0017f,0.0016f,0.0016f,0.0015f,0.0015f,0.0014f,0.0014f,0.0013f,0.0013f,
    0.0013f,0.0012f,0.0012f,0.0011f,0.0011f,0.0011f,0.0010f,0.0010f,0.0010f,0.0009f
};

__device__ __forceinline__ float sigf(float x) {
    return __builtin_amdgcn_rcpf(1.0f + __expf(-x));
}
__device__ __forceinline__ float tanh_fast(float x) {
    return fmaf(2.0f, __builtin_amdgcn_rcpf(1.0f + __expf(-2.0f * x)), -1.0f);
}

// Block = 128 threads = 2 waves over the same 64 sequences.
// Wave p owns hidden units [15p, 15p+15). Weight indices are wave-uniform ->
// compiler emits s_load (SMEM); inner loop is pure v_fma with SGPR weight operand.
// Grid = 512 blocks -> 1024 waves = 1 wave per SIMD across the chip.
__global__ __launch_bounds__(128, 1)
void lstm_trace_kernel(const float* __restrict__ feat,    // [N,12]
                       const float* __restrict__ w_ih1,   // [120,13]
                       const float* __restrict__ w_hh1,   // [120,30]
                       const float* __restrict__ b1,      // [120]
                       const float* __restrict__ w_ih2,   // [4,30]
                       const float* __restrict__ w_hh2,   // [4]
                       const float* __restrict__ b2,      // [4]
                       float* __restrict__ out)           // [N,120]
{
    __shared__ float hx[2][2][16][64];                  // [buf][wave][unit k][lane] 16.4 KB
    __shared__ float p2x[2][4][64];                     // [buf][gate][lane] LSTM2 partials 2 KB
    __shared__ __align__(16) float out_s[64 * 124];     // padded 120->124, 31.7 KB

    const int tid  = threadIdx.x;
    const int lane = tid & 63;
    const int p    = tid >> 6;        // wave id 0/1
    const int ub   = p * 15;          // first owned unit
    const int ob_  = 15 - ub;         // other wave's first unit
    const int seq  = blockIdx.x * 64 + lane;

    // ---- per-sequence constant input projection for this wave's 60 gate rows ----
    float f0[12];
    {
        const float4* fp = reinterpret_cast<const float4*>(feat + seq * 12); // 48B-aligned
        float4 a = fp[0], b = fp[1], cc = fp[2];
        f0[0]=a.x; f0[1]=a.y; f0[2]=a.z; f0[3]=a.w;
        f0[4]=b.x; f0[5]=b.y; f0[6]=b.z; f0[7]=b.w;
        f0[8]=cc.x; f0[9]=cc.y; f0[10]=cc.z; f0[11]=cc.w;
    }

    float projb[60];   // [k][q]
#pragma unroll
    for (int k = 0; k < 15; k++) {
#pragma unroll
        for (int q = 0; q < 4; q++) {
            const int r = q * 30 + ub + k;
            float acc = b1[r];
#pragma unroll
            for (int d = 0; d < 12; d++) acc = fmaf(f0[d], w_ih1[r * 13 + d], acc);
            projb[k * 4 + q] = acc;
        }
    }

    float h[30], c[15], hn[15];
#pragma unroll
    for (int j = 0; j < 30; j++) h[j] = 0.0f;
#pragma unroll
    for (int k = 0; k < 15; k++) c[k] = 0.0f;
    float h2 = 0.0f, c2 = 0.0f;
    const float wh2[4] = { w_hh2[0], w_hh2[1], w_hh2[2], w_hh2[3] };
    const float bb2[4] = { b2[0], b2[1], b2[2], b2[3] };

    int buf = 0;
#pragma unroll 1
    for (int t = 0; t < 120; t++) {
        const float at = AVG_D[t];

        // ---- own 15 units: 4 gate dots each, weights via wave-uniform s_load ----
#pragma unroll
        for (int k = 0; k < 15; k++) {
            const int u = ub + k;
            float a0 = fmaf(at, w_ih1[((0 * 30) + u) * 13 + 12], projb[k * 4 + 0]);
            float a1 = fmaf(at, w_ih1[((1 * 30) + u) * 13 + 12], projb[k * 4 + 1]);
            float a2 = fmaf(at, w_ih1[((2 * 30) + u) * 13 + 12], projb[k * 4 + 2]);
            float a3 = fmaf(at, w_ih1[((3 * 30) + u) * 13 + 12], projb[k * 4 + 3]);
#pragma unroll
            for (int j = 0; j < 30; j++) {
                const float hj = h[j];
                a0 = fmaf(hj, w_hh1[((0 * 30) + u) * 30 + j], a0);
                a1 = fmaf(hj, w_hh1[((1 * 30) + u) * 30 + j], a1);
                a2 = fmaf(hj, w_hh1[((2 * 30) + u) * 30 + j], a2);
                a3 = fmaf(hj, w_hh1[((3 * 30) + u) * 30 + j], a3);
            }
            const float ck = sigf(a1) * c[k] + sigf(a0) * tanh_fast(a2);
            c[k]  = ck;
            hn[k] = sigf(a3) * tanh_fast(ck);
        }

        // ---- LSTM2 partial dots over own units (uniform w_ih2 loads) ----
        float q0 = 0.0f, q1 = 0.0f, q2 = 0.0f, q3 = 0.0f;
#pragma unroll
        for (int k = 0; k < 15; k++) {
            const float hk = hn[k];
            q0 = fmaf(hk, w_ih2[0 * 30 + ub + k], q0);
            q1 = fmaf(hk, w_ih2[1 * 30 + ub + k], q1);
            q2 = fmaf(hk, w_ih2[2 * 30 + ub + k], q2);
            q3 = fmaf(hk, w_ih2[3 * 30 + ub + k], q3);
        }
        if (p == 1) {   // wave-uniform branch
            p2x[buf][0][lane] = q0;
            p2x[buf][1][lane] = q1;
            p2x[buf][2][lane] = q2;
            p2x[buf][3][lane] = q3;
        }

        // ---- publish own new h, conflict-free (lane-contiguous) ----
#pragma unroll
        for (int k = 0; k < 15; k++) hx[buf][p][k][lane] = hn[k];

        __syncthreads();

        // ---- assemble full h for next step ----
#pragma unroll
        for (int k = 0; k < 15; k++) {
            h[ub + k]  = hn[k];
            h[ob_ + k] = hx[buf][1 - p][k][lane];
        }

        // ---- LSTM2 scalar cell on wave 0 ----
        if (p == 0) {
            const float g0 = q0 + p2x[buf][0][lane] + fmaf(h2, wh2[0], bb2[0]);
            const float g1 = q1 + p2x[buf][1][lane] + fmaf(h2, wh2[1], bb2[1]);
            const float g2 = q2 + p2x[buf][2][lane] + fmaf(h2, wh2[2], bb2[2]);
            const float g3 = q3 + p2x[buf][3][lane] + fmaf(h2, wh2[3], bb2[3]);
            c2 = sigf(g1) * c2 + sigf(g0) * tanh_fast(g2);
            h2 = sigf(g3) * tanh_fast(c2);
            out_s[lane * 124 + t] = h2;
        }
        buf ^= 1;
    }

    __syncthreads();
    // ---- coalesced flush: 64 seq x 120 t = 1920 float4, 15 per thread ----
    float* outb = out + (size_t)blockIdx.x * 64 * 120;
#pragma unroll
    for (int it = 0; it < 15; it++) {
        const int fi = it * 128 + tid;
        const int s = fi / 30, j = fi % 30;
        const float4 v = *reinterpret_cast<const float4*>(&out_s[s * 124 + j * 4]);
        *reinterpret_cast<float4*>(&outb[s * 120 + j * 4]) = v;
    }
}

extern "C" void kernel_launch(void* const* d_in, const int* in_sizes, int n_in,
                              void* d_out, int out_size, void* d_ws, size_t ws_size,
                              hipStream_t stream) {
    (void)in_sizes; (void)n_in; (void)out_size; (void)d_ws; (void)ws_size;
    const float* feat  = (const float*)d_in[0];
    const float* w_ih1 = (const float*)d_in[1];
    const float* w_hh1 = (const float*)d_in[2];
    const float* b1    = (const float*)d_in[3];
    const float* w_ih2 = (const float*)d_in[4];
    const float* w_hh2 = (const float*)d_in[5];
    const float* b2    = (const float*)d_in[6];
    float* out = (float*)d_out;

    hipLaunchKernelGGL(lstm_trace_kernel, dim3(512), dim3(128), 0, stream,
                       feat, w_ih1, w_hh1, b1, w_ih2, w_hh2, b2, out);
}

// Round 3
// 1294.944 us; speedup vs baseline: 20.1817x; 20.1817x over previous
//
#include <hip/hip_runtime.h>

// Average-trace constant from the Python module (length 120).
__device__ __constant__ float AVG_D[120] = {
    0.0256f,0.0823f,0.1157f,0.1315f,0.1366f,0.1369f,0.1347f,0.1308f,0.1259f,0.1205f,
    0.1146f,0.1086f,0.1028f,0.0970f,0.0913f,0.0858f,0.0805f,0.0756f,0.0708f,0.0664f,
    0.0623f,0.0584f,0.0549f,0.0515f,0.0485f,0.0456f,0.0429f,0.0404f,0.0381f,0.0360f,
    0.0340f,0.0321f,0.0304f,0.0287f,0.0272f,0.0258f,0.0245f,0.0233f,0.0222f,0.0211f,
    0.0201f,0.0191f,0.0182f,0.0173f,0.0165f,0.0158f,0.0150f,0.0143f,0.0137f,0.0130f,
    0.0125f,0.0119f,0.0114f,0.0108f,0.0104f,0.0099f,0.0095f,0.0091f,0.0087f,0.0083f,
    0.0080f,0.0077f,0.0074f,0.0071f,0.0068f,0.0065f,0.0062f,0.0060f,0.0058f,0.0055f,
    0.0053f,0.0050f,0.0049f,0.0047f,0.0045f,0.0044f,0.0042f,0.0040f,0.0039f,0.0038f,
    0.0036f,0.0034f,0.0033f,0.0032f,0.0031f,0.0030f,0.0029f,0.0028f,0.0027f,0.0026f,
    0.0025f,0.0024f,0.0023f,0.0022f,0.0021f,0.0021f,0.0020f,0.0019f,0.0018f,0.0018f,
    0.0017f,0.0017f,0.0016f,0.0016f,0.0015f,0.0015f,0.0014f,0.0014f,0.0013f,0.0013f,
    0.0013f,0.0012f,0.0012f,0.0011f,0.0011f,0.0011f,0.0010f,0.0010f,0.0010f,0.0009f
};

__device__ __forceinline__ float sigf(float x) {
    return __builtin_amdgcn_rcpf(1.0f + __expf(-x));
}
__device__ __forceinline__ float tanh_fast(float x) {
    return fmaf(2.0f, __builtin_amdgcn_rcpf(1.0f + __expf(-2.0f * x)), -1.0f);
}

// d_ws float layout: [0,3840): wt1p[j][q*32+u] = W_hh1[(q*30+u)*30+j] (padded 30->32)
//                    [3840,3960): wcol[row]    = W_ih1[row*13+12]
__global__ void pack_weights(const float* __restrict__ w_ih1,
                             const float* __restrict__ w_hh1,
                             float* __restrict__ ws) {
    const int tid = threadIdx.x;
    for (int idx = tid; idx < 3840; idx += 256) {
        const int j = idx >> 7, r = idx & 127;
        const int q = r >> 5, u = r & 31;
        ws[idx] = (u < 30) ? w_hh1[(q * 30 + u) * 30 + j] : 0.0f;
    }
    for (int idx = tid; idx < 120; idx += 256) ws[3840 + idx] = w_ih1[idx * 13 + 12];
}

// All offsets inside these templates derive from literals + loop counters only
// -> provably uniform -> s_load (SGPR weights), v_fma v,s,v in the hot loop.
template<int UB>
__device__ __forceinline__ void proj_setup(const float* __restrict__ w_ih1,
                                           const float* __restrict__ b1,
                                           const float* f0, float* projb) {
#pragma unroll
    for (int k = 0; k < 15; k++) {
#pragma unroll
        for (int q = 0; q < 4; q++) {
            const int r = q * 30 + UB + k;
            float acc = b1[r];
#pragma unroll
            for (int d = 0; d < 12; d++) acc = fmaf(f0[d], w_ih1[r * 13 + d], acc);
            projb[k * 4 + q] = acc;
        }
    }
}

template<int UB>
__device__ __forceinline__ void half_step(const float at,
                                          const float* __restrict__ wt1p,
                                          const float* __restrict__ wcolp,
                                          const float* __restrict__ w_ih2,
                                          const float* projb, float* c,
                                          const float (*h_cur)[64], float (*h_nxt)[64],
                                          const int lane,
                                          float& q0, float& q1, float& q2, float& q3) {
    float a[15][4];
#pragma unroll
    for (int k = 0; k < 15; k++) {
#pragma unroll
        for (int q = 0; q < 4; q++)
            a[k][q] = fmaf(at, wcolp[q * 30 + UB + k], projb[k * 4 + q]);
    }

#pragma unroll 5
    for (int j = 0; j < 30; j++) {
        const float hj = h_cur[j][lane];                 // ds_read_b32, 2-way bank (free)
        const float* wr = wt1p + j * 128 + UB;           // uniform -> s_load runs of 15
#pragma unroll
        for (int k = 0; k < 15; k++) {
            a[k][0] = fmaf(hj, wr[0 * 32 + k], a[k][0]);
            a[k][1] = fmaf(hj, wr[1 * 32 + k], a[k][1]);
            a[k][2] = fmaf(hj, wr[2 * 32 + k], a[k][2]);
            a[k][3] = fmaf(hj, wr[3 * 32 + k], a[k][3]);
        }
    }

    q0 = q1 = q2 = q3 = 0.0f;
#pragma unroll
    for (int k = 0; k < 15; k++) {
        const float ck = sigf(a[k][1]) * c[k] + sigf(a[k][0]) * tanh_fast(a[k][2]);
        c[k] = ck;
        const float hk = sigf(a[k][3]) * tanh_fast(ck);
        h_nxt[UB + k][lane] = hk;                        // ds_write_b32, lane-contiguous
        q0 = fmaf(hk, w_ih2[0 * 30 + UB + k], q0);
        q1 = fmaf(hk, w_ih2[1 * 30 + UB + k], q1);
        q2 = fmaf(hk, w_ih2[2 * 30 + UB + k], q2);
        q3 = fmaf(hk, w_ih2[3 * 30 + UB + k], q3);
    }
}

// Block = 128 threads = 2 waves over the same 64 sequences; wave p owns units [15p,15p+15).
// Grid = 512 blocks -> 1024 waves = 1 wave/SIMD chip-wide.
__global__ __launch_bounds__(128, 1)
void lstm_trace_kernel(const float* __restrict__ feat,
                       const float* __restrict__ w_ih1,
                       const float* __restrict__ b1,
                       const float* __restrict__ w_ih2,
                       const float* __restrict__ w_hh2,
                       const float* __restrict__ b2,
                       const float* __restrict__ ws,
                       float* __restrict__ out) {
    __shared__ float h_s[2][32][64];                  // [buf][unit][lane] 16 KB
    __shared__ float p2x[2][4][64];                   // LSTM2 partial exchange 2 KB
    __shared__ __align__(16) float out_s[64 * 124];   // 31.7 KB

    const int tid  = threadIdx.x;
    const int lane = tid & 63;
    const int p    = tid >> 6;
    const int seq  = blockIdx.x * 64 + lane;

    for (int i = tid; i < 2048; i += 128) (&h_s[0][0][0])[i] = 0.0f;  // zero h buf 0

    float f0[12];
    {
        const float4* fp = reinterpret_cast<const float4*>(feat + seq * 12);
        float4 A = fp[0], B = fp[1], C = fp[2];
        f0[0]=A.x; f0[1]=A.y; f0[2]=A.z; f0[3]=A.w;
        f0[4]=B.x; f0[5]=B.y; f0[6]=B.z; f0[7]=B.w;
        f0[8]=C.x; f0[9]=C.y; f0[10]=C.z; f0[11]=C.w;
    }

    float projb[60], c[15];
    if (p == 0) proj_setup<0>(w_ih1, b1, f0, projb);
    else        proj_setup<15>(w_ih1, b1, f0, projb);
#pragma unroll
    for (int k = 0; k < 15; k++) c[k] = 0.0f;

    float h2 = 0.0f, c2 = 0.0f;
    const float wh2[4] = { w_hh2[0], w_hh2[1], w_hh2[2], w_hh2[3] };
    const float bb2[4] = { b2[0], b2[1], b2[2], b2[3] };
    const float* wt1p  = ws;
    const float* wcolp = ws + 3840;

    __syncthreads();

    int cur = 0;
#pragma unroll 1
    for (int t = 0; t < 120; t++) {
        const float at = AVG_D[t];
        float q0, q1, q2, q3;
        if (p == 0) {
            half_step<0>(at, wt1p, wcolp, w_ih2, projb, c, h_s[cur], h_s[cur ^ 1],
                         lane, q0, q1, q2, q3);
        } else {
            half_step<15>(at, wt1p, wcolp, w_ih2, projb, c, h_s[cur], h_s[cur ^ 1],
                          lane, q0, q1, q2, q3);
            p2x[t & 1][0][lane] = q0;
            p2x[t & 1][1][lane] = q1;
            p2x[t & 1][2][lane] = q2;
            p2x[t & 1][3][lane] = q3;
        }
        __syncthreads();
        if (p == 0) {
            const float g0 = q0 + p2x[t & 1][0][lane] + fmaf(h2, wh2[0], bb2[0]);
            const float g1 = q1 + p2x[t & 1][1][lane] + fmaf(h2, wh2[1], bb2[1]);
            const float g2 = q2 + p2x[t & 1][2][lane] + fmaf(h2, wh2[2], bb2[2]);
            const float g3 = q3 + p2x[t & 1][3][lane] + fmaf(h2, wh2[3], bb2[3]);
            c2 = sigf(g1) * c2 + sigf(g0) * tanh_fast(g2);
            h2 = sigf(g3) * tanh_fast(c2);
            out_s[lane * 124 + t] = h2;
        }
        cur ^= 1;
    }

    __syncthreads();
    float* outb = out + (size_t)blockIdx.x * 64 * 120;
#pragma unroll
    for (int it = 0; it < 15; it++) {
        const int fi = it * 128 + tid;
        const int s = fi / 30, j = fi % 30;
        const float4 v = *reinterpret_cast<const float4*>(&out_s[s * 124 + j * 4]);
        *reinterpret_cast<float4*>(&outb[s * 120 + j * 4]) = v;
    }
}

extern "C" void kernel_launch(void* const* d_in, const int* in_sizes, int n_in,
                              void* d_out, int out_size, void* d_ws, size_t ws_size,
                              hipStream_t stream) {
    (void)in_sizes; (void)n_in; (void)out_size; (void)ws_size;
    const float* feat  = (const float*)d_in[0];
    const float* w_ih1 = (const float*)d_in[1];
    const float* w_hh1 = (const float*)d_in[2];
    const float* b1    = (const float*)d_in[3];
    const float* w_ih2 = (const float*)d_in[4];
    const float* w_hh2 = (const float*)d_in[5];
    const float* b2    = (const float*)d_in[6];
    float* ws  = (float*)d_ws;
    float* out = (float*)d_out;

    hipLaunchKernelGGL(pack_weights, dim3(1), dim3(256), 0, stream, w_ih1, w_hh1, ws);
    hipLaunchKernelGGL(lstm_trace_kernel, dim3(512), dim3(128), 0, stream,
                       feat, w_ih1, b1, w_ih2, w_hh2, b2, ws, out);
}

// Round 4
// 1120.819 us; speedup vs baseline: 23.3171x; 1.1554x over previous
//
#include <hip/hip_runtime.h>

// Average-trace constant from the Python module (length 120).
__device__ __constant__ float AVG_D[120] = {
    0.0256f,0.0823f,0.1157f,0.1315f,0.1366f,0.1369f,0.1347f,0.1308f,0.1259f,0.1205f,
    0.1146f,0.1086f,0.1028f,0.0970f,0.0913f,0.0858f,0.0805f,0.0756f,0.0708f,0.0664f,
    0.0623f,0.0584f,0.0549f,0.0515f,0.0485f,0.0456f,0.0429f,0.0404f,0.0381f,0.0360f,
    0.0340f,0.0321f,0.0304f,0.0287f,0.0272f,0.0258f,0.0245f,0.0233f,0.0222f,0.0211f,
    0.0201f,0.0191f,0.0182f,0.0173f,0.0165f,0.0158f,0.0150f,0.0143f,0.0137f,0.0130f,
    0.0125f,0.0119f,0.0114f,0.0108f,0.0104f,0.0099f,0.0095f,0.0091f,0.0087f,0.0083f,
    0.0080f,0.0077f,0.0074f,0.0071f,0.0068f,0.0065f,0.0062f,0.0060f,0.0058f,0.0055f,
    0.0053f,0.0050f,0.0049f,0.0047f,0.0045f,0.0044f,0.0042f,0.0040f,0.0039f,0.0038f,
    0.0036f,0.0034f,0.0033f,0.0032f,0.0031f,0.0030f,0.0029f,0.0028f,0.0027f,0.0026f,
    0.0025f,0.0024f,0.0023f,0.0022f,0.0021f,0.0021f,0.0020f,0.0019f,0.0018f,0.0018f,
    0.0017f,0.0017f,0.0016f,0.0016f,0.0015f,0.0015f,0.0014f,0.0014f,0.0013f,0.0013f,
    0.0013f,0.0012f,0.0012f,0.0011f,0.0011f,0.0011f,0.0010f,0.0010f,0.0010f,0.0009f
};

__device__ __forceinline__ float sigf(float x) {
    return __builtin_amdgcn_rcpf(1.0f + __expf(-x));
}
__device__ __forceinline__ float tanh_fast(float x) {
    return fmaf(2.0f, __builtin_amdgcn_rcpf(1.0f + __expf(-2.0f * x)), -1.0f);
}

// d_ws float layout:
//   [0, 3840):    wt[j][q][32u] = W_hh1[(q*30+u)*30+j]   (u<30, pad to 32)
//   [3840, 3960): wcol[q*30+u]  = W_ih1[(q*30+u)*13+12]
__global__ void pack_weights(const float* __restrict__ w_ih1,
                             const float* __restrict__ w_hh1,
                             float* __restrict__ ws) {
    const int tid = threadIdx.x;
    for (int idx = tid; idx < 3840; idx += 256) {
        const int u = idx & 31, q = (idx >> 5) & 3, j = idx >> 7;
        ws[idx] = (u < 30) ? w_hh1[(q * 30 + u) * 30 + j] : 0.0f;
    }
    for (int idx = tid; idx < 120; idx += 256) ws[3840 + idx] = w_ih1[idx * 13 + 12];
}

// Block = 128 threads = 2 waves over the same 64 sequences.
// Wave p (readfirstlane -> uniform SGPR) owns units [15p,15p+15).
// Hot loop: h[30] in VGPRs, weights via s_load (SGPR), pure v_fma. h exchanged
// once per step through double-buffered LDS. Grid 512 -> 1024 waves = 1/SIMD.
__global__ __launch_bounds__(128, 1)
void lstm_trace_kernel(const float* __restrict__ feat,
                       const float* __restrict__ w_ih1,
                       const float* __restrict__ b1,
                       const float* __restrict__ w_ih2,
                       const float* __restrict__ w_hh2,
                       const float* __restrict__ b2,
                       const float* __restrict__ ws,
                       float* __restrict__ out) {
    __shared__ float hx[2][2][16][64];                // [buf][wave][k][lane] 16.4 KB
    __shared__ float p2x[2][4][64];                   // LSTM2 partials 2 KB
    __shared__ __align__(16) float out_s[64 * 124];   // 31.7 KB

    const int tid  = threadIdx.x;
    const int lane = tid & 63;
    const int p    = __builtin_amdgcn_readfirstlane(tid >> 6);  // uniform wave id
    const int UB   = p * 15;                                    // uniform unit base
    const int seq  = blockIdx.x * 64 + lane;

    float f0[12];
    {
        const float4* fp = reinterpret_cast<const float4*>(feat + seq * 12);
        float4 A = fp[0], B = fp[1], C = fp[2];
        f0[0]=A.x; f0[1]=A.y; f0[2]=A.z; f0[3]=A.w;
        f0[4]=B.x; f0[5]=B.y; f0[6]=B.z; f0[7]=B.w;
        f0[8]=C.x; f0[9]=C.y; f0[10]=C.z; f0[11]=C.w;
    }

    // Per-sequence constant input projection; rows are uniform -> s_load weights.
    float projb[60];   // [k*4+q]
#pragma unroll
    for (int k = 0; k < 15; k++) {
#pragma unroll
        for (int q = 0; q < 4; q++) {
            const int r = q * 30 + UB + k;
            float acc = b1[r];
#pragma unroll
            for (int d = 0; d < 12; d++) acc = fmaf(f0[d], w_ih1[r * 13 + d], acc);
            projb[k * 4 + q] = acc;
        }
    }

    float h[30], c[15];
#pragma unroll
    for (int j = 0; j < 30; j++) h[j] = 0.0f;
#pragma unroll
    for (int k = 0; k < 15; k++) c[k] = 0.0f;
    float h2 = 0.0f, c2 = 0.0f;
    const float wh2[4] = { w_hh2[0], w_hh2[1], w_hh2[2], w_hh2[3] };
    const float bb2[4] = { b2[0], b2[1], b2[2], b2[3] };

#pragma unroll 1
    for (int t = 0; t < 120; t++) {
        const float at  = AVG_D[t];
        const int   buf = t & 1;

        // ---- 60 gate accumulators, init with avg-column term ----
        float a0[15], a1[15], a2[15], a3[15];
#pragma unroll
        for (int k = 0; k < 15; k++) {
            a0[k] = fmaf(at, ws[3840 + 0 * 30 + UB + k], projb[k * 4 + 0]);
            a1[k] = fmaf(at, ws[3840 + 1 * 30 + UB + k], projb[k * 4 + 1]);
            a2[k] = fmaf(at, ws[3840 + 2 * 30 + UB + k], projb[k * 4 + 2]);
            a3[k] = fmaf(at, ws[3840 + 3 * 30 + UB + k], projb[k * 4 + 3]);
        }

        // ---- recurrent matmul: h (VGPR) x W_hh (SGPR via s_load) ----
#pragma unroll
        for (int j = 0; j < 30; j++) {
            const float hj = h[j];
            const float* wj = ws + j * 128 + UB;
#pragma unroll
            for (int k = 0; k < 15; k++) {
                a0[k] = fmaf(hj, wj[0 * 32 + k], a0[k]);
                a1[k] = fmaf(hj, wj[1 * 32 + k], a1[k]);
                a2[k] = fmaf(hj, wj[2 * 32 + k], a2[k]);
                a3[k] = fmaf(hj, wj[3 * 32 + k], a3[k]);
            }
        }

        // ---- activations, publish new h, LSTM2 partial dots ----
        float q0 = 0.0f, q1 = 0.0f, q2 = 0.0f, q3 = 0.0f;
#pragma unroll
        for (int k = 0; k < 15; k++) {
            const float ck = sigf(a1[k]) * c[k] + sigf(a0[k]) * tanh_fast(a2[k]);
            c[k] = ck;
            const float hk = sigf(a3[k]) * tanh_fast(ck);
            hx[buf][p][k][lane] = hk;
            q0 = fmaf(hk, w_ih2[0 * 30 + UB + k], q0);
            q1 = fmaf(hk, w_ih2[1 * 30 + UB + k], q1);
            q2 = fmaf(hk, w_ih2[2 * 30 + UB + k], q2);
            q3 = fmaf(hk, w_ih2[3 * 30 + UB + k], q3);
        }
        if (p == 1) {
            p2x[buf][0][lane] = q0;
            p2x[buf][1][lane] = q1;
            p2x[buf][2][lane] = q2;
            p2x[buf][3][lane] = q3;
        }

        __syncthreads();

        // ---- refresh full h from LDS (both halves; uniform code, no hn[]) ----
#pragma unroll
        for (int k = 0; k < 15; k++) {
            h[k]      = hx[buf][0][k][lane];
            h[15 + k] = hx[buf][1][k][lane];
        }

        // ---- LSTM2 scalar cell on wave 0 ----
        if (p == 0) {
            const float g0 = q0 + p2x[buf][0][lane] + fmaf(h2, wh2[0], bb2[0]);
            const float g1 = q1 + p2x[buf][1][lane] + fmaf(h2, wh2[1], bb2[1]);
            const float g2 = q2 + p2x[buf][2][lane] + fmaf(h2, wh2[2], bb2[2]);
            const float g3 = q3 + p2x[buf][3][lane] + fmaf(h2, wh2[3], bb2[3]);
            c2 = sigf(g1) * c2 + sigf(g0) * tanh_fast(g2);
            h2 = sigf(g3) * tanh_fast(c2);
            out_s[lane * 124 + t] = h2;
        }
    }

    __syncthreads();
    // ---- coalesced flush: 64 seq x 120 t = 1920 float4, 15 per thread ----
    float* outb = out + (size_t)blockIdx.x * 64 * 120;
#pragma unroll
    for (int it = 0; it < 15; it++) {
        const int fi = it * 128 + tid;
        const int s = fi / 30, j = fi % 30;
        const float4 v = *reinterpret_cast<const float4*>(&out_s[s * 124 + j * 4]);
        *reinterpret_cast<float4*>(&outb[s * 120 + j * 4]) = v;
    }
}

extern "C" void kernel_launch(void* const* d_in, const int* in_sizes, int n_in,
                              void* d_out, int out_size, void* d_ws, size_t ws_size,
                              hipStream_t stream) {
    (void)in_sizes; (void)n_in; (void)out_size; (void)ws_size;
    const float* feat  = (const float*)d_in[0];
    const float* w_ih1 = (const float*)d_in[1];
    const float* w_hh1 = (const float*)d_in[2];
    const float* b1    = (const float*)d_in[3];
    const float* w_ih2 = (const float*)d_in[4];
    const float* w_hh2 = (const float*)d_in[5];
    const float* b2    = (const float*)d_in[6];
    float* ws  = (float*)d_ws;
    float* out = (float*)d_out;

    hipLaunchKernelGGL(pack_weights, dim3(1), dim3(256), 0, stream, w_ih1, w_hh1, ws);
    hipLaunchKernelGGL(lstm_trace_kernel, dim3(512), dim3(128), 0, stream,
                       feat, w_ih1, b1, w_ih2, w_hh2, b2, ws, out);
}